// Round 1
// baseline (1042.050 us; speedup 1.0000x reference)
//
#include <hip/hip_runtime.h>
#include <hip/hip_bf16.h>

#define NH 4
#define HD 32
#define DIM 128
#define NTOK 49
#define BLOCK 256

typedef __attribute__((ext_vector_type(8))) short short8;
typedef __attribute__((ext_vector_type(4))) float f32x4;

// strides in elements (all row strides 16-byte aligned for ds_read_b128)
#define XB_S 136   // bf16, 272 B/row
#define QK_S 264   // bf16, 528 B/row
#define VT_S 72    // bf16, 144 B/row
#define P_S  72    // bf16

// LDS byte offsets
// Region A [0, 18432):     xb (13,328) consumed by af loads; then vt (18,432) aliases it
// Region B [18432, 44304): qk (49*264*2 = 25,872); after b2 aliased by ao(13,328)+P(9,216)
#define OFF_XB   0
#define OFF_VT   0
#define OFF_QK   18432
#define OFF_AO   18432
#define OFF_P    31760      // 4 slabs * 16*72*2 = 4*2304 -> ends at 40,976
#define OFF_BT   44304
#define SMEM_SZ  44368

__device__ __forceinline__ short f2bf(float f) {
    union { float f; unsigned u; } v; v.f = f;
    unsigned r = (v.u + 0x7FFFu + ((v.u >> 16) & 1u)) >> 16;
    return (short)r;
}

// Pre-swizzle weights into MFMA B-fragment order: [nt][kt][lane][8] bf16.
// B-frag (16x16x32): lane l holds B[k = kt*32 + (l>>4)*8 + j][n = nt*16 + (l&15)].
__global__ void prep_kernel(const float* __restrict__ wq,
                            const float* __restrict__ wp,
                            short* __restrict__ ws) {
    int t = blockIdx.x * 256 + threadIdx.x;   // 65,536 total
    if (t < 49152) {                           // w_qkv: 24 nt * 4 kt * 64 * 8
        int j = t & 7, lane = (t >> 3) & 63, kt = (t >> 9) & 3, nt = t >> 11;
        int n = nt * 16 + (lane & 15);
        int k = kt * 32 + (lane >> 4) * 8 + j;
        ws[t] = f2bf(wq[k * 384 + n]);
    } else {
        int u = t - 49152;                     // w_proj: 8 nt * 4 kt * 64 * 8
        int j = u & 7, lane = (u >> 3) & 63, kt = (u >> 9) & 3, nt = u >> 11;
        int n = nt * 16 + (lane & 15);
        int k = kt * 32 + (lane >> 4) * 8 + j;
        ws[t] = f2bf(wp[k * 128 + n]);
    }
}

__global__ __launch_bounds__(BLOCK, 3)
void win_attn_kernel(const float* __restrict__ x,
                     const float* __restrict__ b_qkv,
                     const float* __restrict__ b_proj,
                     const float* __restrict__ bias_table,
                     const short* __restrict__ ws,     // swizzled weights
                     float* __restrict__ out)
{
    __shared__ __align__(16) char smem[SMEM_SZ];
    short* xb = (short*)(smem + OFF_XB);
    short* vt = (short*)(smem + OFF_VT);
    short* qk = (short*)(smem + OFF_QK);
    short* ao = (short*)(smem + OFF_AO);
    float* bt = (float*)(smem + OFF_BT);

    const int tid = threadIdx.x;
    const int w   = tid >> 6;        // wave id (0..3)
    const int l   = tid & 63;        // lane
    const int lm  = l & 15;
    const int q4  = l >> 4;          // quad

    const int blk = blockIdx.x;
    const int b  = blk >> 12;
    const int wy = (blk >> 6) & 63;
    const int wx = blk & 63;
    const int imgBase = b * 448 * 448 * DIM;

    const short* wqkv_ws  = ws;
    const short* wproj_ws = ws + 49152;

    // ---------------- Phase 1: stage x -> xb (bf16), bias table --------------
    for (int i = tid; i < NTOK * 32; i += BLOCK) {
        const int tok = i >> 5;
        const int c4  = i & 31;
        const int r = tok / 7, c = tok % 7;
        const float4 v = *(const float4*)(x + imgBase + ((wy*7 + r)*448 + (wx*7 + c))*DIM + c4*4);
        short4 s4;
        s4.x = f2bf(v.x); s4.y = f2bf(v.y); s4.z = f2bf(v.z); s4.w = f2bf(v.w);
        *(short4*)(xb + tok * XB_S + c4 * 4) = s4;
    }
    if (tid < 13) bt[tid] = bias_table[tid];
    __syncthreads();   // b0: xb staged

    // ---------------- Phase 2: QKV GEMM (49x128 @ 128x384) -----------------
    {
        short8 af[4][4];   // [mt][kt] A-frags from xb
        #pragma unroll
        for (int mt = 0; mt < 4; ++mt) {
            int row = 16*mt + lm; if (row > 48) row = 48;
            #pragma unroll
            for (int kt = 0; kt < 4; ++kt)
                af[mt][kt] = *(const short8*)(xb + row * XB_S + kt*32 + q4*8);
        }
        short8 bf[2][4];
        {   const int nt0 = w * 6;
            #pragma unroll
            for (int kt = 0; kt < 4; ++kt)
                bf[0][kt] = *(const short8*)(wqkv_ws + ((nt0*4 + kt)*64 + l)*8);
        }
        __syncthreads();   // b0.5: xb fully consumed into registers; vt may alias it now

        #pragma unroll
        for (int t = 0; t < 6; ++t) {
            const int nt = w * 6 + t;
            if (t < 5) {
                const int ntn = nt + 1;
                #pragma unroll
                for (int kt = 0; kt < 4; ++kt)
                    bf[(t+1)&1][kt] = *(const short8*)(wqkv_ws + ((ntn*4 + kt)*64 + l)*8);
            }
            const int col = nt * 16 + lm;
            const float bq = b_qkv[col];
            f32x4 acc[4] = { {0,0,0,0},{0,0,0,0},{0,0,0,0},{0,0,0,0} };
            #pragma unroll
            for (int kt = 0; kt < 4; ++kt) {
                #pragma unroll
                for (int mt = 0; mt < 4; ++mt)
                    acc[mt] = __builtin_amdgcn_mfma_f32_16x16x32_bf16(
                                  af[mt][kt], bf[t&1][kt], acc[mt], 0, 0, 0);
            }
            const bool isV = (col >= 256);   // wave-uniform per nt
            #pragma unroll
            for (int mt = 0; mt < 4; ++mt) {
                if (isV) {
                    // lane holds 4 consecutive token-rows at fixed channel: one b64 write.
                    // Rows >= 49 hold finite garbage; they are multiplied by exactly-zero
                    // P columns in PV, so no pad-zeroing is needed.
                    short4 pv;
                    pv.x = f2bf(acc[mt][0] + bq);
                    pv.y = f2bf(acc[mt][1] + bq);
                    pv.z = f2bf(acc[mt][2] + bq);
                    pv.w = f2bf(acc[mt][3] + bq);
                    *(short4*)(vt + (col - 256) * VT_S + 16*mt + q4*4) = pv;
                } else {
                    #pragma unroll
                    for (int r = 0; r < 4; ++r) {
                        const int row = 16*mt + q4*4 + r;
                        if (row < NTOK)
                            qk[row * QK_S + col] = f2bf(acc[mt][r] + bq);
                    }
                }
            }
        }
    }
    __syncthreads();   // b1: qkv staged

    // ---------------- Phase 3: attention, wave = head ------------------------
    {
        const int h = w;
        short8 qf[4], kf[4], vf[2][2];
        #pragma unroll
        for (int mt = 0; mt < 4; ++mt) {
            int row = 16*mt + lm; if (row > 48) row = 48;
            qf[mt] = *(const short8*)(qk + row * QK_S + 32*h + q4*8);
        }
        #pragma unroll
        for (int nt = 0; nt < 4; ++nt) {
            int row = 16*nt + lm; if (row > 48) row = 48;
            kf[nt] = *(const short8*)(qk + row * QK_S + 128 + 32*h + q4*8);
        }
        #pragma unroll
        for (int n2 = 0; n2 < 2; ++n2)
            #pragma unroll
            for (int k2 = 0; k2 < 2; ++k2)
                vf[n2][k2] = *(const short8*)(vt + (32*h + 16*n2 + lm) * VT_S + k2*32 + q4*8);
        __syncthreads();   // b2: qk consumed into registers; ao/P aliasing safe

        short* p_slab = (short*)(smem + OFF_P) + h * (16 * P_S);
        const float scale = 0.17677669529663687f;

        // per-lane column divmods (cols = nt*16 + lm), hoisted out of mt loop
        int rj[4], cj[4];
        #pragma unroll
        for (int nt = 0; nt < 4; ++nt) {
            const int c = nt*16 + lm;
            rj[nt] = c / 7; cj[nt] = c - rj[nt]*7;
        }

        // NOTE: no __syncthreads() inside this loop — s/p/ao data is wave-private;
        // same-wave LDS ordering is handled by compiler waitcnts.
        for (int mt = 0; mt < 4; ++mt) {
            f32x4 sacc[4];
            #pragma unroll
            for (int nt = 0; nt < 4; ++nt)
                sacc[nt] = __builtin_amdgcn_mfma_f32_16x16x32_bf16(
                               qf[mt], kf[nt], (f32x4){0,0,0,0}, 0, 0, 0);

            // row/col indices for bias: lane owns rows 16mt+q4*4+r, cols nt*16+lm
            int ri[4], ci[4];
            #pragma unroll
            for (int r = 0; r < 4; ++r) {
                int rg = 16*mt + q4*4 + r; if (rg > 48) rg = 48;
                ri[r] = rg / 7; ci[r] = rg - ri[r]*7;
            }

            // in-register softmax: logits + bias, row-max over lm axis
            float mrow[4] = {-3e38f, -3e38f, -3e38f, -3e38f};
            #pragma unroll
            for (int nt = 0; nt < 4; ++nt) {
                #pragma unroll
                for (int r = 0; r < 4; ++r) {
                    float lv;
                    if (nt < 3 || lm == 0)   // col < 49
                        lv = sacc[nt][r] * scale
                           + bt[ri[r] - rj[nt] + 6] + bt[ci[r] - cj[nt] + 6];
                    else
                        lv = -3e38f;
                    sacc[nt][r] = lv;
                    mrow[r] = fmaxf(mrow[r], lv);
                }
            }
            #pragma unroll
            for (int r = 0; r < 4; ++r) {
                mrow[r] = fmaxf(mrow[r], __shfl_xor(mrow[r], 1, 64));
                mrow[r] = fmaxf(mrow[r], __shfl_xor(mrow[r], 2, 64));
                mrow[r] = fmaxf(mrow[r], __shfl_xor(mrow[r], 4, 64));
                mrow[r] = fmaxf(mrow[r], __shfl_xor(mrow[r], 8, 64));
            }
            float srow[4] = {0.f, 0.f, 0.f, 0.f};
            #pragma unroll
            for (int nt = 0; nt < 4; ++nt) {
                #pragma unroll
                for (int r = 0; r < 4; ++r) {
                    const float e = __expf(sacc[nt][r] - mrow[r]);  // invalid cols -> 0
                    sacc[nt][r] = e;
                    srow[r] += e;
                }
            }
            #pragma unroll
            for (int r = 0; r < 4; ++r) {
                srow[r] += __shfl_xor(srow[r], 1, 64);
                srow[r] += __shfl_xor(srow[r], 2, 64);
                srow[r] += __shfl_xor(srow[r], 4, 64);
                srow[r] += __shfl_xor(srow[r], 8, 64);
            }
            #pragma unroll
            for (int r = 0; r < 4; ++r) {
                const float inv = __builtin_amdgcn_rcpf(srow[r]);
                #pragma unroll
                for (int nt = 0; nt < 4; ++nt)
                    p_slab[(q4*4 + r) * P_S + nt*16 + lm] = f2bf(sacc[nt][r] * inv);
            }

            // PV: O(16x32) += P(16x64) @ V(64x32)   (same-wave LDS turnaround)
            short8 pf[2];
            #pragma unroll
            for (int k2 = 0; k2 < 2; ++k2)
                pf[k2] = *(const short8*)(p_slab + lm * P_S + k2*32 + q4*8);
            f32x4 oacc[2] = { {0,0,0,0},{0,0,0,0} };
            #pragma unroll
            for (int n2 = 0; n2 < 2; ++n2)
                #pragma unroll
                for (int k2 = 0; k2 < 2; ++k2)
                    oacc[n2] = __builtin_amdgcn_mfma_f32_16x16x32_bf16(
                                   pf[k2], vf[n2][k2], oacc[n2], 0, 0, 0);
            #pragma unroll
            for (int n2 = 0; n2 < 2; ++n2)
                #pragma unroll
                for (int r = 0; r < 4; ++r) {
                    const int row = 16*mt + q4*4 + r;
                    if (row < NTOK)
                        ao[row * XB_S + 32*h + 16*n2 + lm] = f2bf(oacc[n2][r]);
                }
        }
    }
    __syncthreads();   // b3: all attn-out written

    // ---------------- Phase 4: out proj (49x128 @ 128x128) -------------------
    {
        short8 af[4][4];
        #pragma unroll
        for (int mt = 0; mt < 4; ++mt) {
            int row = 16*mt + lm; if (row > 48) row = 48;
            #pragma unroll
            for (int kt = 0; kt < 4; ++kt)
                af[mt][kt] = *(const short8*)(ao + row * XB_S + kt*32 + q4*8);
        }
        #pragma unroll
        for (int t = 0; t < 2; ++t) {
            const int nt = w * 2 + t;
            short8 bf[4];
            #pragma unroll
            for (int kt = 0; kt < 4; ++kt)
                bf[kt] = *(const short8*)(wproj_ws + ((nt*4 + kt)*64 + l)*8);
            const int col = nt * 16 + lm;
            const float bp = b_proj[col];
            f32x4 acc[4] = { {0,0,0,0},{0,0,0,0},{0,0,0,0},{0,0,0,0} };
            #pragma unroll
            for (int kt = 0; kt < 4; ++kt)
                #pragma unroll
                for (int mt = 0; mt < 4; ++mt)
                    acc[mt] = __builtin_amdgcn_mfma_f32_16x16x32_bf16(
                                  af[mt][kt], bf[kt], acc[mt], 0, 0, 0);
            #pragma unroll
            for (int mt = 0; mt < 4; ++mt)
                #pragma unroll
                for (int r = 0; r < 4; ++r) {
                    const int row = 16*mt + q4*4 + r;
                    if (row < NTOK) {
                        const int tr = row / 7, tc = row % 7;
                        out[imgBase + ((wy*7 + tr)*448 + (wx*7 + tc))*DIM + col]
                            = acc[mt][r] + bp;
                    }
                }
        }
    }
}

extern "C" void kernel_launch(void* const* d_in, const int* in_sizes, int n_in,
                              void* d_out, int out_size, void* d_ws, size_t ws_size,
                              hipStream_t stream) {
    const float* x          = (const float*)d_in[0];
    const float* w_qkv      = (const float*)d_in[1];
    const float* b_qkv      = (const float*)d_in[2];
    const float* w_proj     = (const float*)d_in[3];
    const float* b_proj     = (const float*)d_in[4];
    const float* bias_table = (const float*)d_in[5];
    float* out = (float*)d_out;
    short* ws  = (short*)d_ws;

    hipLaunchKernelGGL(prep_kernel, dim3(256), dim3(256), 0, stream,
                       w_qkv, w_proj, ws);
    hipLaunchKernelGGL(win_attn_kernel, dim3(16384), dim3(BLOCK), 0, stream,
                       x, b_qkv, b_proj, bias_table, ws, out);
}